// Round 3
// baseline (170.914 us; speedup 1.0000x reference)
//
#include <hip/hip_runtime.h>
#include <math.h>

// Chamfer distance, N=M=16384, D=3, fp32.
// R3: single-kernel. Inner math forced to v_pk_fma_f32 (VOP3P) with
// op_sel broadcasts of the j-point components (no v_mov splats):
//   d_pair = a*(-2bx) + (a*(-2by) + (a*(-2bz) + ||b||^2))   [3 pk_fma / 2 pairs]
// min via v_min3_f32 over 2 j's. ||a||^2 re-added at epilogue (min commutes).
// NPER=16 i-points/thread so one broadcast LDS read feeds 2048 pairs/wave-iter
// (R2 evidence: broadcast ds_read costs full LDS-pipe bandwidth).
// Per-point result via atomicMin(uint) on nonneg floats; last-finished block
// does sqrt+sum -> out. ws memset 0x7F inits both permin (3.39e38) and the
// completion counter (0x7F7F7F7F). Graph = memset + 1 kernel.

typedef float v2f __attribute__((ext_vector_type(2)));

constexpr int NPTS    = 16384;
constexpr int THREADS = 256;
constexpr int NPER    = 16;                 // i-points per thread
constexpr int IPB     = THREADS * NPER;     // 4096 i-points per block
constexpr int IBLK    = NPTS / IPB;         // 4 i-blocks per pass
constexpr int JSPLIT  = 128;                // j-chunks per pass
constexpr int JCHUNK  = NPTS / JSPLIT;      // 128 j-points per block
constexpr int GRID    = 2 * IBLK * JSPLIT;  // 1024 blocks
constexpr unsigned CNT0 = 0x7F7F7F7Fu;      // counter init from 0x7F memset
constexpr float INF_F = 3.402823466e+38f;

static_assert(2 * JCHUNK == THREADS, "staging assumes one v2f slot per thread");

// d = a * bcast(q.lo) + bcast(q.hi)   (chain start: a*(-2bz) + ||b||^2)
static __device__ __forceinline__ v2f pk_fma_zw(v2f a, v2f qzw) {
  v2f d;
  asm("v_pk_fma_f32 %0, %1, %2, %2 op_sel:[0,0,1] op_sel_hi:[1,0,1]"
      : "=v"(d) : "v"(a), "v"(qzw));
  return d;
}
// d = a * bcast(q.hi) + c
static __device__ __forceinline__ v2f pk_fma_hi(v2f a, v2f q, v2f c) {
  v2f d;
  asm("v_pk_fma_f32 %0, %1, %2, %3 op_sel:[0,1,0] op_sel_hi:[1,1,1]"
      : "=v"(d) : "v"(a), "v"(q), "v"(c));
  return d;
}
// d = a * bcast(q.lo) + c
static __device__ __forceinline__ v2f pk_fma_lo(v2f a, v2f q, v2f c) {
  v2f d;
  asm("v_pk_fma_f32 %0, %1, %2, %3 op_sel:[0,0,0] op_sel_hi:[1,0,1]"
      : "=v"(d) : "v"(a), "v"(q), "v"(c));
  return d;
}

__global__ __launch_bounds__(THREADS, 4) void chamfer_main(
    const float* __restrict__ p1, const float* __restrict__ p2,
    unsigned* __restrict__ permin, unsigned* __restrict__ counter,
    float* __restrict__ out) {
  __shared__ v2f slds[2 * JCHUNK];  // [2p]={-2x,-2y}, [2p+1]={-2z,||b||^2}
  __shared__ float red[THREADS / 64];
  __shared__ int is_last;

  const int b    = blockIdx.x;
  const int pass = b >> 9;            // GRID/2 = 512 blocks per pass
  const int rem  = b & 511;
  const int ib   = rem & (IBLK - 1);
  const int c    = rem >> 2;          // j-chunk index (IBLK=4)

  const float* __restrict__ src = (pass == 0) ? p1 : p2;  // "i" side
  const float* __restrict__ oth = (pass == 0) ? p2 : p1;  // "j" side

  const int tid = threadIdx.x;

  // ---- stage j-chunk into LDS (one v2f slot per thread) ----
  {
    const int p  = tid >> 1;
    const int gj = (c * JCHUNK + p) * 3;
    const float x = oth[gj + 0], y = oth[gj + 1], z = oth[gj + 2];
    v2f val;
    if (tid & 1) { val.x = -2.0f * z; val.y = fmaf(x, x, fmaf(y, y, z * z)); }
    else         { val.x = -2.0f * x; val.y = -2.0f * y; }
    slds[tid] = val;
  }

  // ---- load 16 i-points into packed v2f registers ----
  const int ibase = ib * IPB + tid;
  v2f ax[NPER / 2], ay[NPER / 2], az[NPER / 2];
#pragma unroll
  for (int g = 0; g < NPER / 2; ++g) {
    const int ia = (ibase + (2 * g) * THREADS) * 3;
    const int ib2 = (ibase + (2 * g + 1) * THREADS) * 3;
    ax[g].x = src[ia + 0]; ax[g].y = src[ib2 + 0];
    ay[g].x = src[ia + 1]; ay[g].y = src[ib2 + 1];
    az[g].x = src[ia + 2]; az[g].y = src[ib2 + 2];
  }

  float m[NPER];
#pragma unroll
  for (int k = 0; k < NPER; ++k) m[k] = INF_F;

  __syncthreads();

  // ---- inner loop: 2 j-points per iteration, 16 i-points per thread ----
#pragma unroll 2
  for (int j = 0; j < JCHUNK; j += 2) {
    const v2f qaxy = slds[2 * j + 0];
    const v2f qazw = slds[2 * j + 1];
    const v2f qbxy = slds[2 * j + 2];
    const v2f qbzw = slds[2 * j + 3];
#pragma unroll
    for (int g = 0; g < NPER / 2; ++g) {
      v2f ta = pk_fma_zw(az[g], qazw);
      ta = pk_fma_hi(ay[g], qaxy, ta);
      ta = pk_fma_lo(ax[g], qaxy, ta);
      v2f tb = pk_fma_zw(az[g], qbzw);
      tb = pk_fma_hi(ay[g], qbxy, tb);
      tb = pk_fma_lo(ax[g], qbxy, tb);
      m[2 * g]     = fminf(fminf(ta.x, tb.x), m[2 * g]);      // v_min3_f32
      m[2 * g + 1] = fminf(fminf(ta.y, tb.y), m[2 * g + 1]);
    }
  }

  // ---- epilogue: re-add ||a||^2, clamp >=0, atomicMin into permin ----
  unsigned* __restrict__ pm = permin + pass * NPTS;
#pragma unroll
  for (int g = 0; g < NPER / 2; ++g) {
    const v2f sav = __builtin_elementwise_fma(
        ax[g], ax[g],
        __builtin_elementwise_fma(ay[g], ay[g], az[g] * az[g]));
    const float v0 = fmaxf(sav.x + m[2 * g], 0.0f);
    const float v1 = fmaxf(sav.y + m[2 * g + 1], 0.0f);
    atomicMin(pm + ibase + (2 * g) * THREADS, __float_as_uint(v0));
    atomicMin(pm + ibase + (2 * g + 1) * THREADS, __float_as_uint(v1));
  }

  // ---- last finished block reduces permin -> out[0] ----
  __threadfence();  // release our atomics before signaling
  if (tid == 0) {
    const unsigned old = atomicAdd(counter, 1u);
    is_last = (old == CNT0 + (unsigned)(GRID - 1));
  }
  __syncthreads();
  if (is_last) {
    __threadfence();  // acquire: see all blocks' atomicMins
    const float* __restrict__ pmf = (const float*)permin;
    float s = 0.0f;
    for (int p = tid; p < 2 * NPTS; p += THREADS) s += sqrtf(pmf[p]);
    for (int off = 32; off > 0; off >>= 1) s += __shfl_down(s, off, 64);
    if ((tid & 63) == 0) red[tid >> 6] = s;
    __syncthreads();
    if (tid == 0) out[0] = red[0] + red[1] + red[2] + red[3];
  }
}

extern "C" void kernel_launch(void* const* d_in, const int* in_sizes, int n_in,
                              void* d_out, int out_size, void* d_ws, size_t ws_size,
                              hipStream_t stream) {
  const float* p1 = (const float*)d_in[0];
  const float* p2 = (const float*)d_in[1];
  float* out = (float*)d_out;
  unsigned* ws = (unsigned*)d_ws;  // [0, 2*NPTS): permin bits; [2*NPTS]: counter

  // 0x7F7F7F7F = 3.3961e38f as float (> any sq-dist) and the counter's start.
  hipMemsetAsync(d_ws, 0x7F, (size_t)(2 * NPTS + 1) * sizeof(unsigned), stream);
  chamfer_main<<<GRID, THREADS, 0, stream>>>(p1, p2, ws, ws + 2 * NPTS, out);
}

// Round 4
// 117.352 us; speedup vs baseline: 1.4564x; 1.4564x over previous
//
#include <hip/hip_runtime.h>
#include <math.h>

// Chamfer distance, N=M=16384, D=3, fp32.
// R4: scalar-fma inner loop (v_pk_fma_f32 is HALF-RATE on gfx950 -- the
// 157 TF fp32 peak is the scalar v_fma rate; R3 measured this), 3 fma +
// 0.5 v_min3 per pair = 3.5 lane-ops/pair => ~24 us VALU floor.
// ||a||^2 hoisted out of the j-loop (min commutes with +const).
// NPER=16 i-points/thread: one broadcast ds_read_b128 per j feeds 16 pairs
// -> LDS pipe ~10 us/CU, under the VALU time.
// Contention-free partial stores (R3's 4.2M contended atomicMins wrote
// through to HBM and serialized); reduce kernel does min/sqrt/sum with one
// atomicAdd per block into memset-zeroed out[0]. ~50 us harness overhead is
// fixed regardless of node count (R1-R3 evidence).

constexpr int NPTS    = 16384;
constexpr int THREADS = 256;
constexpr int NPER    = 16;                  // i-points per thread
constexpr int IPB     = THREADS * NPER;      // 4096 i-points per block
constexpr int IBLK    = NPTS / IPB;          // 4 i-blocks per pass
constexpr int TS      = 128;                 // j-tile in LDS (2 KB)
constexpr float INF_F = 3.402823466e+38f;

__global__ __launch_bounds__(THREADS, 4) void chamfer_main(
    const float* __restrict__ p1, const float* __restrict__ p2,
    float* __restrict__ partial, int jsplit) {
  __shared__ float4 lds[TS];  // per j: {-2x, -2y, -2z, ||b||^2}

  const int per_pass = IBLK * jsplit;
  const int b    = blockIdx.x;
  const int pass = b / per_pass;
  const int rem  = b - pass * per_pass;
  const int c    = rem / IBLK;   // j-chunk index
  const int ib   = rem - c * IBLK;

  const float* __restrict__ src = (pass == 0) ? p1 : p2;  // "i" side
  const float* __restrict__ oth = (pass == 0) ? p2 : p1;  // "j" side

  const int tid = threadIdx.x;
  const int ibase = ib * IPB + tid;

  // ---- load 16 i-points into registers ----
  float ax[NPER], ay[NPER], az[NPER];
#pragma unroll
  for (int g = 0; g < NPER; ++g) {
    const int ia = (ibase + g * THREADS) * 3;
    ax[g] = src[ia + 0];
    ay[g] = src[ia + 1];
    az[g] = src[ia + 2];
  }

  // running min of (||b||^2 - 2 a.b); ||a||^2 re-added in the reduce kernel
  float m[NPER];
#pragma unroll
  for (int g = 0; g < NPER; ++g) m[g] = INF_F;

  const int jchunk = NPTS / jsplit;
  const int j0 = c * jchunk;

  for (int t0 = 0; t0 < jchunk; t0 += TS) {
    __syncthreads();  // protect LDS from previous tile's readers
    if (tid < TS) {
      const int gj = (j0 + t0 + tid) * 3;
      const float x = oth[gj + 0], y = oth[gj + 1], z = oth[gj + 2];
      lds[tid] = make_float4(-2.0f * x, -2.0f * y, -2.0f * z,
                             fmaf(x, x, fmaf(y, y, z * z)));
    }
    __syncthreads();

#pragma unroll 2
    for (int j = 0; j < TS; j += 2) {
      const float4 q = lds[j];
      const float4 r = lds[j + 1];
#pragma unroll
      for (int g = 0; g < NPER; ++g) {
        const float dq = fmaf(ax[g], q.x, fmaf(ay[g], q.y, fmaf(az[g], q.z, q.w)));
        const float dr = fmaf(ax[g], r.x, fmaf(ay[g], r.y, fmaf(az[g], r.z, r.w)));
        m[g] = fminf(fminf(dq, dr), m[g]);  // v_min3_f32
      }
    }
  }

  float* __restrict__ dst = partial + (size_t)(pass * jsplit + c) * NPTS;
#pragma unroll
  for (int g = 0; g < NPER; ++g) dst[ibase + g * THREADS] = m[g];
}

// One thread per point (2*16384): min over jsplit partials, re-add ||a||^2,
// sqrt, block-sum, one atomicAdd per block into out[0] (zeroed by memset).
__global__ __launch_bounds__(THREADS) void chamfer_reduce(
    const float* __restrict__ p1, const float* __restrict__ p2,
    const float* __restrict__ partial, float* __restrict__ out, int jsplit) {
  const int p = blockIdx.x * THREADS + threadIdx.x;  // 0..32767
  const int pass = p >> 14;
  const int i = p & (NPTS - 1);
  const float* __restrict__ pts = (pass == 0) ? p1 : p2;

  const float x = pts[i * 3 + 0], y = pts[i * 3 + 1], z = pts[i * 3 + 2];
  const float sa = fmaf(x, x, fmaf(y, y, z * z));

  const float* __restrict__ base = partial + (size_t)pass * jsplit * NPTS + i;
  float m0 = INF_F, m1 = INF_F;
  int c = 0;
  for (; c + 1 < jsplit; c += 2) {
    m0 = fminf(m0, base[(size_t)c * NPTS]);
    m1 = fminf(m1, base[(size_t)(c + 1) * NPTS]);
  }
  if (c < jsplit) m0 = fminf(m0, base[(size_t)c * NPTS]);
  float d = sqrtf(fmaxf(sa + fminf(m0, m1), 0.0f));

  for (int off = 32; off > 0; off >>= 1) d += __shfl_down(d, off, 64);
  __shared__ float red[THREADS / 64];
  const int wave = threadIdx.x >> 6;
  const int lane = threadIdx.x & 63;
  if (lane == 0) red[wave] = d;
  __syncthreads();
  if (threadIdx.x == 0) {
    float s = 0.0f;
    for (int w = 0; w < THREADS / 64; ++w) s += red[w];
    atomicAdd(out, s);
  }
}

extern "C" void kernel_launch(void* const* d_in, const int* in_sizes, int n_in,
                              void* d_out, int out_size, void* d_ws, size_t ws_size,
                              hipStream_t stream) {
  const float* p1 = (const float*)d_in[0];
  const float* p2 = (const float*)d_in[1];
  float* out = (float*)d_out;
  float* partial = (float*)d_ws;

  // jsplit=128 -> 1024 blocks (4/CU, 16 waves/CU); scratch 2*jsplit*NPTS
  // floats (16 MB). Degrade if ws is small.
  int jsplit = 128;
  while (jsplit > 1 &&
         (size_t)(2 * jsplit * NPTS) * sizeof(float) > ws_size) {
    jsplit >>= 1;
  }

  const int main_grid = 2 * IBLK * jsplit;     // 1024 @ jsplit=128
  const int red_grid  = (2 * NPTS) / THREADS;  // 128

  hipMemsetAsync(out, 0, sizeof(float), stream);
  chamfer_main<<<main_grid, THREADS, 0, stream>>>(p1, p2, partial, jsplit);
  chamfer_reduce<<<red_grid, THREADS, 0, stream>>>(p1, p2, partial, out, jsplit);
}